// Round 3
// baseline (3119.935 us; speedup 1.0000x reference)
//
#include <hip/hip_runtime.h>

#define HID 256
#define BM 64
#define BN 64
#define BK 32
#define AS_LD 68
#define BS_LD 68

typedef unsigned short u16;
typedef unsigned int u32;

static __device__ __forceinline__ float bf2f(u16 b) {
    u32 u = ((u32)b) << 16;
    return __uint_as_float(u);
}
static __device__ __forceinline__ u16 f2bf(float f) {
    u32 u = __float_as_uint(f);
    u32 r = (u + 0x7FFFu + ((u >> 16) & 1u)) >> 16;  // RN-even
    return (u16)r;
}
static __device__ __forceinline__ float loadA(const float* p) { return *p; }
static __device__ __forceinline__ float loadA(const u16* p)   { return bf2f(*p); }

struct us4 { u16 x, y, z, w; };

// C[M][256] = relu( A1[M][K1] @ BT1[K1][256] + (A2 ? A2[M][K2] @ BT2[K2][256] : 0) + bias )
// A1: fp32 or bf16; A2: fp32 (or nullptr); BT*: fp32 pre-transposed; C: bf16.
template <typename TA1>
__global__ __launch_bounds__(256) void gemm_dual(
    const TA1* __restrict__ A1, int lda1, int M, int K1,
    const float* __restrict__ BT1,
    const float* __restrict__ A2, int lda2, int K2,
    const float* __restrict__ BT2,
    const float* __restrict__ bias,    // [256] fp32 or nullptr
    u16* __restrict__ C)               // [M][256] bf16
{
    __shared__ __align__(16) float As[BK][AS_LD];
    __shared__ __align__(16) float Bs[BK][BS_LD];

    const int t    = threadIdx.x;
    const int row0 = blockIdx.x * BM;
    const int col0 = blockIdx.y * BN;

    const int i0 = (t >> 4) * 4;
    const int j0 = (t & 15) * 4;

    float acc[4][4] = {};

    const int a_kk  = t & 31;
    const int a_i2b = t >> 5;
    const int b_j4  = t & 15;
    const int b_kkb = t >> 4;

    // ---- product 1 ----
    for (int k0 = 0; k0 < K1; k0 += BK) {
        #pragma unroll
        for (int half = 0; half < 2; ++half) {
            const int i2 = a_i2b + 8 * half;
            const int k  = k0 + a_kk;
            float v[4];
            #pragma unroll
            for (int r = 0; r < 4; ++r) {
                const int row = row0 + i2 * 4 + r;
                v[r] = (row < M && k < K1) ? loadA(&A1[(size_t)row * lda1 + k]) : 0.f;
            }
            *(float4*)&As[a_kk][i2 * 4] = make_float4(v[0], v[1], v[2], v[3]);
        }
        #pragma unroll
        for (int half = 0; half < 2; ++half) {
            const int kk = b_kkb + 16 * half;
            const int k  = k0 + kk;
            float4 v = make_float4(0.f, 0.f, 0.f, 0.f);
            if (k < K1) v = *(const float4*)&BT1[(size_t)k * HID + col0 + b_j4 * 4];
            *(float4*)&Bs[kk][b_j4 * 4] = v;
        }
        __syncthreads();
        #pragma unroll
        for (int kk = 0; kk < BK; ++kk) {
            const float4 af = *(const float4*)&As[kk][i0];
            const float4 bf = *(const float4*)&Bs[kk][j0];
            const float a[4] = {af.x, af.y, af.z, af.w};
            const float b[4] = {bf.x, bf.y, bf.z, bf.w};
            #pragma unroll
            for (int r = 0; r < 4; ++r)
                #pragma unroll
                for (int c = 0; c < 4; ++c)
                    acc[r][c] += a[r] * b[c];
        }
        __syncthreads();
    }

    // ---- product 2 (optional, A2 fp32) ----
    if (A2) {
        for (int k0 = 0; k0 < K2; k0 += BK) {
            #pragma unroll
            for (int half = 0; half < 2; ++half) {
                const int i2 = a_i2b + 8 * half;
                const int k  = k0 + a_kk;
                float v[4];
                #pragma unroll
                for (int r = 0; r < 4; ++r) {
                    const int row = row0 + i2 * 4 + r;
                    v[r] = (row < M && k < K2) ? A2[(size_t)row * lda2 + k] : 0.f;
                }
                *(float4*)&As[a_kk][i2 * 4] = make_float4(v[0], v[1], v[2], v[3]);
            }
            #pragma unroll
            for (int half = 0; half < 2; ++half) {
                const int kk = b_kkb + 16 * half;
                const int k  = k0 + kk;
                float4 v = make_float4(0.f, 0.f, 0.f, 0.f);
                if (k < K2) v = *(const float4*)&BT2[(size_t)k * HID + col0 + b_j4 * 4];
                *(float4*)&Bs[kk][b_j4 * 4] = v;
            }
            __syncthreads();
            #pragma unroll
            for (int kk = 0; kk < BK; ++kk) {
                const float4 af = *(const float4*)&As[kk][i0];
                const float4 bf = *(const float4*)&Bs[kk][j0];
                const float a[4] = {af.x, af.y, af.z, af.w};
                const float b[4] = {bf.x, bf.y, bf.z, bf.w};
                #pragma unroll
                for (int r = 0; r < 4; ++r)
                    #pragma unroll
                    for (int c = 0; c < 4; ++c)
                        acc[r][c] += a[r] * b[c];
            }
            __syncthreads();
        }
    }

    // ---- epilogue: +bias, relu, bf16 store ----
    float4 bia = make_float4(0.f, 0.f, 0.f, 0.f);
    if (bias) bia = *(const float4*)&bias[col0 + j0];
    #pragma unroll
    for (int r = 0; r < 4; ++r) {
        const int row = row0 + i0 + r;
        if (row >= M) break;
        const size_t base = (size_t)row * HID + col0 + j0;
        float4 v = make_float4(acc[r][0] + bia.x, acc[r][1] + bia.y,
                               acc[r][2] + bia.z, acc[r][3] + bia.w);
        us4 o;
        o.x = f2bf(fmaxf(v.x, 0.f)); o.y = f2bf(fmaxf(v.y, 0.f));
        o.z = f2bf(fmaxf(v.z, 0.f)); o.w = f2bf(fmaxf(v.w, 0.f));
        *(us4*)&C[base] = o;
    }
}

// WT[k][j] = W[j][k]   (W is [256][Kd], fp32)
__global__ void transpose_w(const float* __restrict__ W, float* __restrict__ WT, int Kd)
{
    const int k = blockIdx.x;
    const int j = threadIdx.x;
    WT[(size_t)k * HID + j] = W[(size_t)j * Kd + k];
}

// dst[e][:] = sum_j src[graph[e][j]][:]   (bf16 in/out, fp32 accum)
// also used for the atom-side gather (graph=agraph, n=N)
__global__ void gather_rows(const u16* __restrict__ src, const int* __restrict__ graph,
                            u16* __restrict__ dst, int n)
{
    const int e = blockIdx.x * 4 + (threadIdx.x >> 6);
    if (e >= n) return;
    const int lane = threadIdx.x & 63;
    const int* idx = graph + (size_t)e * 6;
    float s[4] = {0.f, 0.f, 0.f, 0.f};
    #pragma unroll
    for (int j = 0; j < 6; ++j) {
        const int b = idx[j];
        const us4 v = ((const us4*)(src + (size_t)b * HID))[lane];
        s[0] += bf2f(v.x); s[1] += bf2f(v.y); s[2] += bf2f(v.z); s[3] += bf2f(v.w);
    }
    us4 o = { f2bf(s[0]), f2bf(s[1]), f2bf(s[2]), f2bf(s[3]) };
    ((us4*)(dst + (size_t)e * HID))[lane] = o;
}

// per-molecule mean over sorted mol_ids; atomh bf16, out fp32
__global__ void segment_mean(const u16* __restrict__ atomh, const int* __restrict__ mol_ids,
                             float* __restrict__ out, int N)
{
    const int m = blockIdx.x;
    const int t = threadIdx.x;
    __shared__ int s_lo, s_hi;
    if (t == 0) {
        int lo = 0, hi = N;
        while (lo < hi) { int mid = (lo + hi) >> 1; if (mol_ids[mid] < m) lo = mid + 1; else hi = mid; }
        s_lo = lo;
        lo = s_lo; hi = N;
        while (lo < hi) { int mid = (lo + hi) >> 1; if (mol_ids[mid] < m + 1) lo = mid + 1; else hi = mid; }
        s_hi = lo;
    }
    __syncthreads();
    const int lo = s_lo, hi = s_hi;
    float sum = 0.f;
    for (int a = lo; a < hi; ++a) sum += bf2f(atomh[(size_t)a * HID + t]);
    const float cnt = (float)((hi - lo) > 1 ? (hi - lo) : 1);
    out[(size_t)m * HID + t] = sum / cnt;
}

extern "C" void kernel_launch(void* const* d_in, const int* in_sizes, int n_in,
                              void* d_out, int out_size, void* d_ws, size_t ws_size,
                              hipStream_t stream)
{
    const float* fatoms = (const float*)d_in[0];
    const float* fbonds = (const float*)d_in[1];
    const int*   agraph = (const int*)d_in[2];
    const int*   bgraph = (const int*)d_in[3];
    const int*   mol_ids = (const int*)d_in[4];
    const float* W_i = (const float*)d_in[7];
    const float* W_h = (const float*)d_in[8];
    const float* W_o = (const float*)d_in[9];
    const float* b_o = (const float*)d_in[10];

    const int N = in_sizes[0] / 39;       // 100000
    const int E = in_sizes[1] / 50;       // 200001
    const int N_MOLS = 1000;
    const int DEPTH = 6;

    const size_t EH = (size_t)E * HID;

    // ---- workspace: 2 big bf16 buffers + fp32 transposed weights ----
    const size_t need = 2 * EH * sizeof(u16)
                      + ((size_t)50 + 256 + 295) * HID * sizeof(float);
    if (ws_size < need) return;  // clean absmax-fail signal if ws still too small

    u16* msg = (u16*)d_ws;                      // [E][256]
    u16* nei = msg + EH;                        // [E][256]  (also atom-gather dst [N][256])
    float* wit = (float*)(nei + EH);            // [50][256]
    float* wht = wit + (size_t)50 * HID;        // [256][256]
    float* wot = wht + (size_t)HID * HID;       // [295][256]
    u16* atomh = msg;                           // [N][256] alias (msg dead after atom gather)

    float* out = (float*)d_out;

    transpose_w<<<dim3(50),  dim3(256), 0, stream>>>(W_i, wit, 50);
    transpose_w<<<dim3(256), dim3(256), 0, stream>>>(W_h, wht, 256);
    transpose_w<<<dim3(295), dim3(256), 0, stream>>>(W_o, wot, 295);

    const int gmE = (E + BM - 1) / BM;
    const int gmN = (N + BM - 1) / BM;

    // layer 0: msg = relu(fbonds @ W_i.T)
    gemm_dual<float><<<dim3(gmE, HID / BN), dim3(256), 0, stream>>>(
        fbonds, 50, E, 50, wit,
        nullptr, 0, 0, nullptr, nullptr, msg);

    // hidden layers: nei = gather(msg); msg = relu(nei@W_h.T + fbonds@W_i.T)
    for (int it = 0; it < DEPTH - 1; ++it) {
        gather_rows<<<dim3((E + 3) / 4), dim3(256), 0, stream>>>(msg, bgraph, nei, E);
        gemm_dual<u16><<<dim3(gmE, HID / BN), dim3(256), 0, stream>>>(
            nei, HID, E, HID, wht,
            fbonds, 50, 50, wit, nullptr, msg);
    }

    // atom-side gather: nei[n] = sum_j msg[agraph[n][j]]
    gather_rows<<<dim3((N + 3) / 4), dim3(256), 0, stream>>>(msg, agraph, nei, N);

    // atomh = relu(nei @ W_o[:,39:].T + fatoms @ W_o[:,:39].T + b_o)
    gemm_dual<u16><<<dim3(gmN, HID / BN), dim3(256), 0, stream>>>(
        nei, HID, N, HID, wot + (size_t)39 * HID,
        fatoms, 39, 39, wot, b_o, atomh);

    // per-molecule mean
    segment_mean<<<dim3(N_MOLS), dim3(256), 0, stream>>>(atomh, mol_ids, out, N);
}

// Round 4
// 1411.476 us; speedup vs baseline: 2.2104x; 2.2104x over previous
//
#include <hip/hip_runtime.h>

#define HID 256

typedef unsigned short u16;
typedef unsigned int u32;
typedef short bf16x8 __attribute__((ext_vector_type(8)));
typedef float f32x4 __attribute__((ext_vector_type(4)));
typedef u16 u16x8 __attribute__((ext_vector_type(8)));

static __device__ __forceinline__ float bf2f(u16 b) {
    u32 u = ((u32)b) << 16;
    return __uint_as_float(u);
}
static __device__ __forceinline__ u16 f2bf(float f) {
    u32 u = __float_as_uint(f);
    return (u16)((u + 0x7FFFu + ((u >> 16) & 1u)) >> 16);  // RN-even
}

// async 16B global -> LDS (wave-uniform LDS base + lane*16)
static __device__ __forceinline__ void glds16(const void* g, void* l) {
    __builtin_amdgcn_global_load_lds(
        (const __attribute__((address_space(1))) void*)g,
        (__attribute__((address_space(3))) void*)l, 16, 0, 0);
}

// ---------------------------------------------------------------------------
// C[M][256] = relu( A1[M][256](bf16) @ B[k=0..k1*32) + A2[M][K2](fp32) @ B[tail] + bias )
// B operand: WB [256 cols][ldb k] bf16 (B^T layout, contiguous k), k-concatenated.
// Tile: 128x128, 4 waves, each 64x64 via 4x4 of mfma_f32_16x16x32_bf16.
// ---------------------------------------------------------------------------
__global__ __launch_bounds__(256) void mfma_gemm(
    const u16* __restrict__ A1, int k1chunks,          // lda1 = 256
    const float* __restrict__ A2, int lda2, int K2, int k2chunks,
    const u16* __restrict__ WB, int ldb,               // [256][ldb] bf16
    const float* __restrict__ bias,                    // [256] fp32 or nullptr
    u16* __restrict__ C, int M)                        // [M][256] bf16
{
    __shared__ __align__(16) u16 As[128 * 32];  // [row][k] 64B rows
    __shared__ __align__(16) u16 Bs[128 * 32];  // [col][k] 64B rows

    const int t    = threadIdx.x;
    const int w    = t >> 6;
    const int lane = t & 63;
    const int row0 = blockIdx.x * 128;
    const int col0 = blockIdx.y * 128;

    const int wr = (w & 1) * 64;   // wave's row block
    const int wc = (w >> 1) * 64;  // wave's col block

    const int qr = lane >> 2;      // staging: row within 16-row group
    const int kq = lane & 3;       // staging: 16B granule within 64B row

    const int fr = lane & 15;      // frag row/col
    const int fq = lane >> 4;      // frag k-quad

    f32x4 acc[4][4] = {};

    const int nchunks = k1chunks + k2chunks;

    for (int kc = 0; kc < nchunks; ++kc) {
        // ---- stage B tile (always bf16, global_load_lds) ----
        {
            const u16* gB = WB + (size_t)(col0 + w * 32 + qr) * ldb + kc * 32 + kq * 8;
            glds16(gB,            Bs + w * 1024);
            glds16(gB + 16 * ldb, Bs + w * 1024 + 512);
        }
        // ---- stage A tile ----
        if (kc < k1chunks) {
            const u16* gA = A1 + (size_t)(row0 + w * 32 + qr) * 256 + kc * 32 + kq * 8;
            glds16(gA,            As + w * 1024);
            glds16(gA + 16 * 256, As + w * 1024 + 512);
        } else {
            // fp32 tail with on-the-fly bf16 conversion (bounds-checked)
            const int kb = (kc - k1chunks) * 32;
            const int r  = t >> 1;
            const int h  = t & 1;
            const int gr = row0 + r;
            u16 tmp[16];
            #pragma unroll
            for (int i = 0; i < 16; ++i) {
                const int k = kb + h * 16 + i;
                float v = (gr < M && k < K2) ? A2[(size_t)gr * lda2 + k] : 0.f;
                tmp[i] = f2bf(v);
            }
            uint4* dst = (uint4*)(As + r * 32 + h * 16);
            dst[0] = ((const uint4*)tmp)[0];
            dst[1] = ((const uint4*)tmp)[1];
        }
        __syncthreads();

        // ---- fragments + MFMA ----
        bf16x8 af[4], bfr[4];
        #pragma unroll
        for (int i = 0; i < 4; ++i)
            af[i] = *(const bf16x8*)(As + (wr + i * 16 + fr) * 32 + fq * 8);
        #pragma unroll
        for (int j = 0; j < 4; ++j)
            bfr[j] = *(const bf16x8*)(Bs + (wc + j * 16 + fr) * 32 + fq * 8);
        #pragma unroll
        for (int i = 0; i < 4; ++i)
            #pragma unroll
            for (int j = 0; j < 4; ++j)
                acc[i][j] = __builtin_amdgcn_mfma_f32_16x16x32_bf16(af[i], bfr[j], acc[i][j], 0, 0, 0);
        __syncthreads();
    }

    // ---- epilogue: +bias, relu, bf16 store ----
    // C/D layout: col = lane&15, row = (lane>>4)*4 + reg
    #pragma unroll
    for (int j = 0; j < 4; ++j) {
        const int gc = col0 + wc + j * 16 + fr;
        const float b = bias ? bias[gc] : 0.f;
        #pragma unroll
        for (int i = 0; i < 4; ++i) {
            const int grb = row0 + wr + i * 16 + fq * 4;
            #pragma unroll
            for (int r = 0; r < 4; ++r) {
                const int gr = grb + r;
                if (gr < M)
                    C[(size_t)gr * 256 + gc] = f2bf(fmaxf(acc[i][j][r] + b, 0.f));
            }
        }
    }
}

// ---------------------------------------------------------------------------
// WB[n][k] bf16: k<k1 -> src1[n][off1+k]; k1<=k<k1+k2 -> src2[n][off2+k-k1]; else 0
// ---------------------------------------------------------------------------
__global__ void build_wb(const float* __restrict__ src1, int lds1, int off1, int k1,
                         const float* __restrict__ src2, int lds2, int off2, int k2,
                         u16* __restrict__ dst, int ldd)
{
    const int n = blockIdx.x;  // 0..255
    for (int k = threadIdx.x; k < ldd; k += blockDim.x) {
        float v = 0.f;
        if (k < k1)           v = src1[(size_t)n * lds1 + off1 + k];
        else if (k < k1 + k2) v = src2[(size_t)n * lds2 + off2 + (k - k1)];
        dst[(size_t)n * ldd + k] = f2bf(v);
    }
}

// dst[e][:] = sum_j src[graph[e][j]][:]   (bf16 in/out, fp32 accum, 16B lanes)
__global__ void gather_rows(const u16* __restrict__ src, const int* __restrict__ graph,
                            u16* __restrict__ dst, int n)
{
    const int e = blockIdx.x * 8 + (threadIdx.x >> 5);
    if (e >= n) return;
    const int p = threadIdx.x & 31;      // 16B granule
    const int* idx = graph + (size_t)e * 6;
    float s[8] = {};
    #pragma unroll
    for (int j = 0; j < 6; ++j) {
        const int b = idx[j];
        const u16x8 v = *(const u16x8*)(src + (size_t)b * 256 + p * 8);
        #pragma unroll
        for (int i = 0; i < 8; ++i) s[i] += bf2f(v[i]);
    }
    u16x8 o;
    #pragma unroll
    for (int i = 0; i < 8; ++i) o[i] = f2bf(s[i]);
    *(u16x8*)(dst + (size_t)e * 256 + p * 8) = o;
}

// per-molecule mean over sorted mol_ids; atomh bf16, out fp32
__global__ void segment_mean(const u16* __restrict__ atomh, const int* __restrict__ mol_ids,
                             float* __restrict__ out, int N)
{
    const int m = blockIdx.x;
    const int t = threadIdx.x;
    __shared__ int s_lo, s_hi;
    if (t == 0) {
        int lo = 0, hi = N;
        while (lo < hi) { int mid = (lo + hi) >> 1; if (mol_ids[mid] < m) lo = mid + 1; else hi = mid; }
        s_lo = lo;
        lo = s_lo; hi = N;
        while (lo < hi) { int mid = (lo + hi) >> 1; if (mol_ids[mid] < m + 1) lo = mid + 1; else hi = mid; }
        s_hi = lo;
    }
    __syncthreads();
    const int lo = s_lo, hi = s_hi;
    float sum = 0.f;
    for (int a = lo; a < hi; ++a) sum += bf2f(atomh[(size_t)a * HID + t]);
    const float cnt = (float)((hi - lo) > 1 ? (hi - lo) : 1);
    out[(size_t)m * HID + t] = sum / cnt;
}

extern "C" void kernel_launch(void* const* d_in, const int* in_sizes, int n_in,
                              void* d_out, int out_size, void* d_ws, size_t ws_size,
                              hipStream_t stream)
{
    const float* fatoms = (const float*)d_in[0];
    const float* fbonds = (const float*)d_in[1];
    const int*   agraph = (const int*)d_in[2];
    const int*   bgraph = (const int*)d_in[3];
    const int*   mol_ids = (const int*)d_in[4];
    const float* W_i = (const float*)d_in[7];
    const float* W_h = (const float*)d_in[8];
    const float* W_o = (const float*)d_in[9];
    const float* b_o = (const float*)d_in[10];

    const int N = in_sizes[0] / 39;       // 100000
    const int E = in_sizes[1] / 50;       // 200001
    const int N_MOLS = 1000;
    const int DEPTH = 6;

    const size_t EH = (size_t)E * HID;

    const size_t wbh_sz = (size_t)256 * 320;
    const size_t wbi_sz = (size_t)256 * 64;
    const size_t wbo_sz = (size_t)256 * 320;
    const size_t need = (2 * EH + wbh_sz + wbi_sz + wbo_sz) * sizeof(u16);
    if (ws_size < need) return;

    u16* msg = (u16*)d_ws;              // [E][256]
    u16* nei = msg + EH;                // [E][256]
    u16* wbh = nei + EH;                // [256][320]  W_h || W_i || 0
    u16* wbi = wbh + wbh_sz;            // [256][64]   W_i || 0
    u16* wbo = wbi + wbi_sz;            // [256][320]  W_o[:,39:] || W_o[:,:39] || 0
    u16* atomh = msg;                   // [N][256] alias (msg dead after atom gather)

    float* out = (float*)d_out;

    build_wb<<<dim3(256), dim3(64), 0, stream>>>(W_h, 256, 0, 256, W_i, 50, 0, 50, wbh, 320);
    build_wb<<<dim3(256), dim3(64), 0, stream>>>(W_i, 50, 0, 50, W_i, 50, 0, 0, wbi, 64);
    build_wb<<<dim3(256), dim3(64), 0, stream>>>(W_o, 295, 39, 256, W_o, 295, 0, 39, wbo, 320);

    const int gE = (E + 127) / 128;     // 1563
    const int gN = (N + 127) / 128;     // 782

    // layer 0: msg = relu(fbonds @ W_i.T)
    mfma_gemm<<<dim3(gE, 2), dim3(256), 0, stream>>>(
        nullptr, 0, fbonds, 50, 50, 2, wbi, 64, nullptr, msg, E);

    // hidden layers: nei = gather(msg); msg = relu(nei@W_h.T + fbonds@W_i.T)
    for (int it = 0; it < DEPTH - 1; ++it) {
        gather_rows<<<dim3((E + 7) / 8), dim3(256), 0, stream>>>(msg, bgraph, nei, E);
        mfma_gemm<<<dim3(gE, 2), dim3(256), 0, stream>>>(
            nei, 8, fbonds, 50, 50, 2, wbh, 320, nullptr, msg, E);
    }

    // atom-side gather: nei[n] = sum_j msg[agraph[n][j]]
    gather_rows<<<dim3((N + 7) / 8), dim3(256), 0, stream>>>(msg, agraph, nei, N);

    // atomh = relu(nei @ W_o[:,39:].T + fatoms @ W_o[:,:39].T + b_o)
    mfma_gemm<<<dim3(gN, 2), dim3(256), 0, stream>>>(
        nei, 8, fatoms, 39, 39, 2, wbo, 320, b_o, atomh, N);

    // per-molecule mean
    segment_mean<<<dim3(N_MOLS), dim3(256), 0, stream>>>(atomh, mol_ids, out, N);
}

// Round 5
// 1381.587 us; speedup vs baseline: 2.2582x; 1.0216x over previous
//
#include <hip/hip_runtime.h>

#define HID 256

typedef unsigned short u16;
typedef unsigned int u32;
typedef short bf16x8 __attribute__((ext_vector_type(8)));
typedef float f32x4 __attribute__((ext_vector_type(4)));
typedef u16 u16x8 __attribute__((ext_vector_type(8)));

static __device__ __forceinline__ float bf2f(u16 b) {
    u32 u = ((u32)b) << 16;
    return __uint_as_float(u);
}
static __device__ __forceinline__ u16 f2bf(float f) {
    u32 u = __float_as_uint(f);
    return (u16)((u + 0x7FFFu + ((u >> 16) & 1u)) >> 16);  // RN-even
}

#define AS_STRIDE 40   // u16 units; 80 B = 20 dwords -> 2-way LDS aliasing (free)

// ---------------------------------------------------------------------------
// Fused gather + dual GEMM + relu:
//   C[r][:] = relu( (sum_j S[graph[r][j]]) @ WB[k<k1*32] + A2[r] @ WB[tail] + bias )
// Tile 128 rows x 256 cols, 4 waves (each 64x128), mfma_f32_16x16x32_bf16.
// Operand-swapped MFMA: lane holds 4 consecutive C-columns -> packed 8B stores.
// ---------------------------------------------------------------------------
__global__ __launch_bounds__(256, 2) void fused_layer(
    const u16* __restrict__ S,        // gather source [*][256] bf16 (or nullptr)
    const int* __restrict__ graph,    // [M][6] (or nullptr)
    int k1chunks,                     // 8 for K=256 gather part, 0 for none
    const float* __restrict__ A2, int lda2, int K2, int k2chunks,
    const u16* __restrict__ WB, int ldb,   // [256 cols][ldb k] bf16
    const float* __restrict__ bias,   // [256] fp32 or nullptr
    u16* __restrict__ C, int M)       // [M][256] bf16
{
    __shared__ __align__(16) u16 As[128 * AS_STRIDE];
    __shared__ __align__(16) u16 Bs[256 * AS_STRIDE];

    const int t    = threadIdx.x;
    const int w    = t >> 6;
    const int lane = t & 63;
    const int row0 = blockIdx.x * 128;

    const int wr = (w & 1) * 64;     // wave row block (64 rows)
    const int wc = (w >> 1) * 128;   // wave col block (128 cols)
    const int fr = lane & 15;
    const int fq = lane >> 4;

    // gather tasks: thread handles rows (t>>2) and (t>>2)+64, granule g = t&3
    const int g = t & 3;
    const int r_a = t >> 2;
    const u16* nb[2][6];
    if (k1chunks > 0) {
        #pragma unroll
        for (int s = 0; s < 2; ++s) {
            const int gr_ = row0 + r_a + s * 64;
            #pragma unroll
            for (int j = 0; j < 6; ++j) {
                const int idx = (gr_ < M) ? graph[(size_t)gr_ * 6 + j] : 0;
                nb[s][j] = S + (size_t)idx * 256;
            }
        }
    }

    f32x4 acc[4][8] = {};
    const int nch = k1chunks + k2chunks;

    #pragma unroll 1
    for (int kc = 0; kc < nch; ++kc) {
        const int kb = kc * 32;
        // ---- stage B: 256 cols x 32 k (VALU, L2-hot) ----
        #pragma unroll
        for (int p = 0; p < 4; ++p) {
            const int col = (t >> 2) + 64 * p;
            const u16x8 v = *(const u16x8*)(WB + (size_t)col * ldb + kb + g * 8);
            *(u16x8*)(Bs + col * AS_STRIDE + g * 8) = v;
        }
        // ---- stage A ----
        if (kc < k1chunks) {
            // fused gather: sum 6 neighbor slices (fp32 accum), bf16 to LDS
            #pragma unroll
            for (int s = 0; s < 2; ++s) {
                float sacc[8] = {};
                #pragma unroll
                for (int j = 0; j < 6; ++j) {
                    const u16x8 v = *(const u16x8*)(nb[s][j] + kb + g * 8);
                    #pragma unroll
                    for (int e = 0; e < 8; ++e) sacc[e] += bf2f(v[e]);
                }
                u16x8 o;
                #pragma unroll
                for (int e = 0; e < 8; ++e) o[e] = f2bf(sacc[e]);
                *(u16x8*)(As + (r_a + s * 64) * AS_STRIDE + g * 8) = o;
            }
        } else {
            // fp32 side-input tail with on-the-fly bf16 conversion
            const int kb2 = (kc - k1chunks) * 32;
            const int r = t >> 1, h = t & 1;
            const int gr_ = row0 + r;
            u16 tmp[16];
            #pragma unroll
            for (int i2 = 0; i2 < 16; ++i2) {
                const int k = kb2 + h * 16 + i2;
                const float v = (gr_ < M && k < K2) ? A2[(size_t)gr_ * lda2 + k] : 0.f;
                tmp[i2] = f2bf(v);
            }
            uint4* dst = (uint4*)(As + r * AS_STRIDE + h * 16);
            dst[0] = ((const uint4*)tmp)[0];
            dst[1] = ((const uint4*)tmp)[1];
        }
        __syncthreads();

        // ---- fragments + MFMA (operands swapped: C^T layout per lane) ----
        bf16x8 af[4];
        #pragma unroll
        for (int i = 0; i < 4; ++i)
            af[i] = *(const bf16x8*)(As + (wr + i * 16 + fr) * AS_STRIDE + fq * 8);
        #pragma unroll
        for (int j = 0; j < 8; ++j) {
            const bf16x8 bfv = *(const bf16x8*)(Bs + (wc + j * 16 + fr) * AS_STRIDE + fq * 8);
            #pragma unroll
            for (int i = 0; i < 4; ++i)
                acc[i][j] = __builtin_amdgcn_mfma_f32_16x16x32_bf16(bfv, af[i], acc[i][j], 0, 0, 0);
        }
        __syncthreads();
    }

    // ---- epilogue: lane holds rows (i*16+fr), cols (j*16 + fq*4 .. +3) ----
    #pragma unroll
    for (int j = 0; j < 8; ++j) {
        const int gc = wc + j * 16 + fq * 4;
        float4 bv = make_float4(0.f, 0.f, 0.f, 0.f);
        if (bias) bv = *(const float4*)&bias[gc];
        #pragma unroll
        for (int i = 0; i < 4; ++i) {
            const int gr_ = row0 + wr + i * 16 + fr;
            if (gr_ < M) {
                u16 o[4];
                o[0] = f2bf(fmaxf(acc[i][j][0] + bv.x, 0.f));
                o[1] = f2bf(fmaxf(acc[i][j][1] + bv.y, 0.f));
                o[2] = f2bf(fmaxf(acc[i][j][2] + bv.z, 0.f));
                o[3] = f2bf(fmaxf(acc[i][j][3] + bv.w, 0.f));
                *(uint2*)&C[(size_t)gr_ * 256 + gc] = *(const uint2*)o;
            }
        }
    }
}

// WB[n][k] bf16: k<k1 -> src1[n][off1+k]; k1<=k<k1+k2 -> src2[n][off2+k-k1]; else 0
__global__ void build_wb(const float* __restrict__ src1, int lds1, int off1, int k1,
                         const float* __restrict__ src2, int lds2, int off2, int k2,
                         u16* __restrict__ dst, int ldd)
{
    const int n = blockIdx.x;  // 0..255
    for (int k = threadIdx.x; k < ldd; k += blockDim.x) {
        float v = 0.f;
        if (k < k1)           v = src1[(size_t)n * lds1 + off1 + k];
        else if (k < k1 + k2) v = src2[(size_t)n * lds2 + off2 + (k - k1)];
        dst[(size_t)n * ldd + k] = f2bf(v);
    }
}

// per-molecule mean over sorted mol_ids; atomh bf16, out fp32
__global__ void segment_mean(const u16* __restrict__ atomh, const int* __restrict__ mol_ids,
                             float* __restrict__ out, int N)
{
    const int m = blockIdx.x;
    const int t = threadIdx.x;
    __shared__ int s_lo, s_hi;
    if (t == 0) {
        int lo = 0, hi = N;
        while (lo < hi) { int mid = (lo + hi) >> 1; if (mol_ids[mid] < m) lo = mid + 1; else hi = mid; }
        s_lo = lo;
        lo = s_lo; hi = N;
        while (lo < hi) { int mid = (lo + hi) >> 1; if (mol_ids[mid] < m + 1) lo = mid + 1; else hi = mid; }
        s_hi = lo;
    }
    __syncthreads();
    const int lo = s_lo, hi = s_hi;
    float sum = 0.f;
    for (int a = lo; a < hi; ++a) sum += bf2f(atomh[(size_t)a * HID + t]);
    const float cnt = (float)((hi - lo) > 1 ? (hi - lo) : 1);
    out[(size_t)m * HID + t] = sum / cnt;
}

extern "C" void kernel_launch(void* const* d_in, const int* in_sizes, int n_in,
                              void* d_out, int out_size, void* d_ws, size_t ws_size,
                              hipStream_t stream)
{
    const float* fatoms = (const float*)d_in[0];
    const float* fbonds = (const float*)d_in[1];
    const int*   agraph = (const int*)d_in[2];
    const int*   bgraph = (const int*)d_in[3];
    const int*   mol_ids = (const int*)d_in[4];
    const float* W_i = (const float*)d_in[7];
    const float* W_h = (const float*)d_in[8];
    const float* W_o = (const float*)d_in[9];
    const float* b_o = (const float*)d_in[10];

    const int N = in_sizes[0] / 39;       // 100000
    const int E = in_sizes[1] / 50;       // 200001
    const int N_MOLS = 1000;
    const int DEPTH = 6;

    const size_t EH = (size_t)E * HID;

    const size_t wbh_sz = (size_t)256 * 320;
    const size_t wbi_sz = (size_t)256 * 64;
    const size_t wbo_sz = (size_t)256 * 320;
    const size_t need = (2 * EH + wbh_sz + wbi_sz + wbo_sz) * sizeof(u16);
    if (ws_size < need) return;

    u16* buf0 = (u16*)d_ws;             // [E][256]
    u16* buf1 = buf0 + EH;              // [E][256]
    u16* wbh = buf1 + EH;               // [256][320]  W_h || W_i || 0
    u16* wbi = wbh + wbh_sz;            // [256][64]   W_i || 0
    u16* wbo = wbi + wbi_sz;            // [256][320]  W_o[:,39:] || W_o[:,:39] || 0

    float* out = (float*)d_out;

    build_wb<<<dim3(256), dim3(64), 0, stream>>>(W_h, 256, 0, 256, W_i, 50, 0, 50, wbh, 320);
    build_wb<<<dim3(256), dim3(64), 0, stream>>>(W_i, 50, 0, 50, W_i, 50, 0, 0, wbi, 64);
    build_wb<<<dim3(256), dim3(64), 0, stream>>>(W_o, 295, 39, 256, W_o, 295, 0, 39, wbo, 320);

    const int gE = (E + 127) / 128;     // 1563
    const int gN = (N + 127) / 128;     // 782

    // layer 0: buf0 = relu(fbonds @ W_i.T)
    fused_layer<<<dim3(gE), dim3(256), 0, stream>>>(
        nullptr, nullptr, 0, fbonds, 50, 50, 2, wbi, 64, nullptr, buf0, E);

    // hidden layers (ping-pong): dst = relu(gather(src) @ W_h.T + fbonds @ W_i.T)
    u16* src = buf0;
    u16* dst = buf1;
    for (int it = 0; it < DEPTH - 1; ++it) {
        fused_layer<<<dim3(gE), dim3(256), 0, stream>>>(
            src, bgraph, 8, fbonds, 50, 50, 2, wbh, 320, nullptr, dst, E);
        u16* tmp = src; src = dst; dst = tmp;
    }
    // after 5 layers: src = buf1 (final message), dst = buf0 (free)

    // output layer: atomh = relu(gather_a(src) @ W_o[:,39:].T + fatoms @ W_o[:,:39].T + b_o)
    fused_layer<<<dim3(gN), dim3(256), 0, stream>>>(
        src, agraph, 8, fatoms, 39, 39, 2, wbo, 320, b_o, dst, N);

    // per-molecule mean
    segment_mean<<<dim3(N_MOLS), dim3(256), 0, stream>>>(dst, mol_ids, out, N);
}